// Round 2
// baseline (372.892 us; speedup 1.0000x reference)
//
#include <hip/hip_runtime.h>
#include <hip/hip_bf16.h>

// EdgeGNN: 3x EdgeConv(mean) + final linear.
// Algebra: out_i = relu( h_i @ (Wtop - Wbot) + mean_j(h_j @ Wbot) + b ), 0 if deg==0.
// => GEMM on dense H first (P = H@(Wtop-Wbot) fp32, Q = H@Wbot bf16), then gather-mean of Q.
// Removes the edge-level GEMM (10x FLOPs) AND the 512-wide gather-built A matrix.

typedef short short8 __attribute__((ext_vector_type(8)));
typedef float float4v __attribute__((ext_vector_type(4)));

static __device__ __forceinline__ float bf2f(unsigned short u) {
    union { unsigned int i; float f; } c; c.i = ((unsigned int)u) << 16; return c.f;
}
static __device__ __forceinline__ unsigned short f2bf(float f) {
    union { float f; unsigned int i; } c; c.f = f;
    unsigned int u = c.i;
    return (unsigned short)((u + 0x7FFFu + ((u >> 16) & 1u)) >> 16);  // RNE
}

// ---------------- CSR build ----------------
__global__ void count_kernel(const int* __restrict__ dst, int E, int* __restrict__ deg) {
    int idx = blockIdx.x * 256 + threadIdx.x;
    if (idx < E) atomicAdd(&deg[dst[idx]], 1);
}

__global__ __launch_bounds__(1024) void scan_kernel(const int* __restrict__ deg,
                                                    int* __restrict__ offs,
                                                    int* __restrict__ cursor, int N) {
    __shared__ int sh[1024];
    int t = threadIdx.x;
    int CH = (N + 1023) >> 10;
    int beg = t * CH, end = beg + CH; if (end > N) end = N; if (beg > N) beg = N;
    int s = 0;
    for (int i = beg; i < end; ++i) s += deg[i];
    sh[t] = s;
    __syncthreads();
    for (int off = 1; off < 1024; off <<= 1) {
        int v = 0;
        if (t >= off) v = sh[t - off];
        __syncthreads();
        if (t >= off) sh[t] += v;
        __syncthreads();
    }
    int run = (t > 0) ? sh[t - 1] : 0;
    for (int i = beg; i < end; ++i) {
        offs[i] = run; cursor[i] = run; run += deg[i];
    }
    if (t == 1023) offs[N] = sh[1023];
}

__global__ void fill_kernel(const int* __restrict__ src, const int* __restrict__ dst, int E,
                            int* __restrict__ cursor, int* __restrict__ esrc) {
    int idx = blockIdx.x * 256 + threadIdx.x;
    if (idx < E) {
        int p = atomicAdd(&cursor[dst[idx]], 1);
        esrc[p] = src[idx];
    }
}

// ---------------- fused prep: weight diff+transpose+bf16 (coalesced via LDS tiles) + x->bf16 ----
// blocks 0..191    : layer weights. Wc[n][k]     = bf16(W[k][n] - W[k+256][n])   (n<256)
//                                   Wc[256+n][k] = bf16(W[k+256][n])
// blocks 192..447  : Wf transpose.  Wft[n][k] = bf16(Wf[k][n]), k<1024, n<256
// blocks 448+      : x fp32 -> bf16 into Ucat column block 0 (row stride 1024)
__global__ __launch_bounds__(256)
void prep_kernel(const float* __restrict__ W0, const float* __restrict__ W1,
                 const float* __restrict__ W2, const float* __restrict__ Wf,
                 const float* __restrict__ x,
                 unsigned short* __restrict__ Wc0, unsigned short* __restrict__ Wc1,
                 unsigned short* __restrict__ Wc2, unsigned short* __restrict__ Wft,
                 unsigned short* __restrict__ Ucat, int N) {
    __shared__ float ta[32][33];
    __shared__ float tb[32][33];
    int bb = blockIdx.x;
    int t = threadIdx.x;
    int r0 = t >> 5, c = t & 31;
    if (bb < 192) {
        const float* W = (bb < 64) ? W0 : (bb < 128) ? W1 : W2;
        unsigned short* Wc = (bb < 64) ? Wc0 : (bb < 128) ? Wc1 : Wc2;
        int t64 = bb & 63;
        int k0 = (t64 >> 3) * 32, n0 = (t64 & 7) * 32;
#pragma unroll
        for (int it = 0; it < 4; ++it) {
            int r = r0 + it * 8;
            float a = W[(k0 + r) * 256 + n0 + c];
            float bv = W[(k0 + r + 256) * 256 + n0 + c];
            ta[r][c] = a - bv;
            tb[r][c] = bv;
        }
        __syncthreads();
#pragma unroll
        for (int it = 0; it < 4; ++it) {
            int r = r0 + it * 8;  // row in n-space
            Wc[(n0 + r) * 256 + k0 + c] = f2bf(ta[c][r]);
            Wc[(256 + n0 + r) * 256 + k0 + c] = f2bf(tb[c][r]);
        }
    } else if (bb < 448) {
        int t256 = bb - 192;
        int k0 = (t256 >> 3) * 32, n0 = (t256 & 7) * 32;
#pragma unroll
        for (int it = 0; it < 4; ++it) {
            int r = r0 + it * 8;
            ta[r][c] = Wf[(k0 + r) * 256 + n0 + c];
        }
        __syncthreads();
#pragma unroll
        for (int it = 0; it < 4; ++it) {
            int r = r0 + it * 8;
            Wft[(n0 + r) * 1024 + k0 + c] = f2bf(ta[c][r]);
        }
    } else {
        long base = (long)(bb - 448) * 2048 + t * 8;
        if (base < (long)N * 256) {
            int i = (int)(base >> 8), cc = (int)(base & 255);
            const float4* xp = (const float4*)(x + base);
            float4 v0 = xp[0], v1 = xp[1];
            ushort4 w0, w1;
            w0.x = f2bf(v0.x); w0.y = f2bf(v0.y); w0.z = f2bf(v0.z); w0.w = f2bf(v0.w);
            w1.x = f2bf(v1.x); w1.y = f2bf(v1.y); w1.z = f2bf(v1.z); w1.w = f2bf(v1.w);
            unsigned short* up = Ucat + (long)i * 1024 + cc;
            *(ushort4*)up = w0;
            *(ushort4*)(up + 4) = w1;
        }
    }
}

// ---------------- bf16 MFMA GEMM ----------------
// A: bf16, row stride 1024 (a column window of Ucat). Bt: bf16 [rows=outcols][K].
// MODE 0 (layer): grid.y=4; out cols 0..255 -> P fp32 [M][256]; cols 256..511 -> Qb bf16 [M][256]
// MODE 1 (final): grid.y=2; out fp32 [M][256] + bias
#define BM 128
#define BN 128
#define BK 64
#define LDK 72  // padded LDS row stride (elements)

template <int MODE>
__global__ __launch_bounds__(256)
void gemm_kernel(const unsigned short* __restrict__ A,
                 const unsigned short* __restrict__ Bt,
                 const float* __restrict__ bias,
                 float* __restrict__ P,
                 unsigned short* __restrict__ Qb,
                 float* __restrict__ outF,
                 int M, int K) {
    __shared__ unsigned short ldsA[BM * LDK];
    __shared__ unsigned short ldsB[BN * LDK];
    int t = threadIdx.x;
    int bm = blockIdx.x, bn = blockIdx.y;
    int lane = t & 63, wave = t >> 6;
    int wm = wave >> 1, wn = wave & 1;
    int lr = lane & 15, q = lane >> 4;

    float4v acc[4][4];
#pragma unroll
    for (int i = 0; i < 4; i++)
#pragma unroll
        for (int j = 0; j < 4; j++) { float4v z = {0.f, 0.f, 0.f, 0.f}; acc[i][j] = z; }

    int r = t >> 1;       // staging row 0..127
    int half = t & 1;     // which 64B half of the 128B row-slice
    int rowA = bm * BM + r;
    bool okA = rowA < M;
    const unsigned short* gA = A + (long)rowA * 1024 + half * 32;
    const unsigned short* gB = Bt + (long)(bn * BN + r) * K + half * 32;
    unsigned short* sA = ldsA + r * LDK + half * 32;
    unsigned short* sB = ldsB + r * LDK + half * 32;

    for (int k0 = 0; k0 < K; k0 += BK) {
        uint4 a[4], b[4];
#pragma unroll
        for (int j = 0; j < 4; ++j) a[j] = make_uint4(0, 0, 0, 0);
        if (okA) {
#pragma unroll
            for (int j = 0; j < 4; ++j) a[j] = *(const uint4*)(gA + k0 + j * 8);
        }
#pragma unroll
        for (int j = 0; j < 4; ++j) b[j] = *(const uint4*)(gB + k0 + j * 8);
        __syncthreads();
#pragma unroll
        for (int j = 0; j < 4; ++j) { *(uint4*)(sA + j * 8) = a[j]; *(uint4*)(sB + j * 8) = b[j]; }
        __syncthreads();
        short8 af[4][2], bfr[4][2];
#pragma unroll
        for (int mi = 0; mi < 4; ++mi)
#pragma unroll
            for (int ks = 0; ks < 2; ++ks)
                af[mi][ks] = *(const short8*)(ldsA + (wm * 64 + mi * 16 + lr) * LDK + ks * 32 + q * 8);
#pragma unroll
        for (int ni = 0; ni < 4; ++ni)
#pragma unroll
            for (int ks = 0; ks < 2; ++ks)
                bfr[ni][ks] = *(const short8*)(ldsB + (wn * 64 + ni * 16 + lr) * LDK + ks * 32 + q * 8);
#pragma unroll
        for (int ks = 0; ks < 2; ++ks)
#pragma unroll
            for (int mi = 0; mi < 4; ++mi)
#pragma unroll
                for (int ni = 0; ni < 4; ++ni)
                    acc[mi][ni] = __builtin_amdgcn_mfma_f32_16x16x32_bf16(af[mi][ks], bfr[ni][ks], acc[mi][ni], 0, 0, 0);
    }

    int nBase = bn * BN + wn * 64;
    int rowBase = bm * BM + wm * 64;
#pragma unroll
    for (int mi = 0; mi < 4; ++mi) {
#pragma unroll
        for (int ni = 0; ni < 4; ++ni) {
            int n = nBase + ni * 16 + lr;
            int row0 = rowBase + mi * 16 + q * 4;
#pragma unroll
            for (int rr4 = 0; rr4 < 4; ++rr4) {
                int rr = row0 + rr4;
                if (rr < M) {
                    float v = acc[mi][ni][rr4];
                    if (MODE == 0) {
                        if (n < 256) P[(long)rr * 256 + n] = v;
                        else Qb[(long)rr * 256 + (n - 256)] = f2bf(v);
                    } else {
                        outF[(long)rr * 256 + n] = v + bias[n];
                    }
                }
            }
        }
    }
}

// ---------------- gather-mean + epilogue: one wave per node ----------------
// out_i = relu(P_i + mean_j Q_j + b) if deg>0 else 0; write bf16 into Ucat column block.
__global__ __launch_bounds__(256)
void agg_kernel(const float* __restrict__ P, const unsigned short* __restrict__ Qb,
                const float* __restrict__ bias,
                const int* __restrict__ offs, const int* __restrict__ esrc,
                unsigned short* __restrict__ Ucat, int colOff, int N) {
    int wave = threadIdx.x >> 6, lane = threadIdx.x & 63;
    int i = blockIdx.x * 4 + wave;
    if (i >= N) return;
    int c = lane * 4;
    float4 pv = *(const float4*)(P + (long)i * 256 + c);
    float4 bv = *(const float4*)(bias + c);
    float a0 = 0.f, a1 = 0.f, a2 = 0.f, a3 = 0.f;
    int e0 = offs[i], e1 = offs[i + 1];
    int e = e0;
    for (; e + 4 <= e1; e += 4) {  // 4 outstanding gathers for MLP
        int s0 = esrc[e], s1 = esrc[e + 1], s2 = esrc[e + 2], s3 = esrc[e + 3];
        ushort4 r0 = *(const ushort4*)(Qb + (long)s0 * 256 + c);
        ushort4 r1 = *(const ushort4*)(Qb + (long)s1 * 256 + c);
        ushort4 r2 = *(const ushort4*)(Qb + (long)s2 * 256 + c);
        ushort4 r3 = *(const ushort4*)(Qb + (long)s3 * 256 + c);
        a0 += (bf2f(r0.x) + bf2f(r1.x)) + (bf2f(r2.x) + bf2f(r3.x));
        a1 += (bf2f(r0.y) + bf2f(r1.y)) + (bf2f(r2.y) + bf2f(r3.y));
        a2 += (bf2f(r0.z) + bf2f(r1.z)) + (bf2f(r2.z) + bf2f(r3.z));
        a3 += (bf2f(r0.w) + bf2f(r1.w)) + (bf2f(r2.w) + bf2f(r3.w));
    }
    for (; e < e1; ++e) {
        int s0 = esrc[e];
        ushort4 r0 = *(const ushort4*)(Qb + (long)s0 * 256 + c);
        a0 += bf2f(r0.x); a1 += bf2f(r0.y); a2 += bf2f(r0.z); a3 += bf2f(r0.w);
    }
    int d = e1 - e0;
    float inv = (d > 0) ? 1.0f / (float)d : 0.0f;
    ushort4 w;
    float v0 = (d > 0) ? fmaxf(pv.x + a0 * inv + bv.x, 0.f) : 0.f;
    float v1 = (d > 0) ? fmaxf(pv.y + a1 * inv + bv.y, 0.f) : 0.f;
    float v2 = (d > 0) ? fmaxf(pv.z + a2 * inv + bv.z, 0.f) : 0.f;
    float v3 = (d > 0) ? fmaxf(pv.w + a3 * inv + bv.w, 0.f) : 0.f;
    w.x = f2bf(v0); w.y = f2bf(v1); w.z = f2bf(v2); w.w = f2bf(v3);
    *(ushort4*)(Ucat + (long)i * 1024 + colOff + c) = w;
}

extern "C" void kernel_launch(void* const* d_in, const int* in_sizes, int n_in,
                              void* d_out, int out_size, void* d_ws, size_t ws_size,
                              hipStream_t stream) {
    const float* x = (const float*)d_in[0];
    const int* ei = (const int*)d_in[1];
    const float* W[3] = {(const float*)d_in[2], (const float*)d_in[4], (const float*)d_in[6]};
    const float* b[3] = {(const float*)d_in[3], (const float*)d_in[5], (const float*)d_in[7]};
    const float* Wfp = (const float*)d_in[8];
    const float* bfp = (const float*)d_in[9];

    int N = in_sizes[0] / 256;
    int E = in_sizes[1] / 2;
    const int* src = ei;
    const int* dst = ei + E;

    char* p = (char*)d_ws;
    auto alloc = [&](size_t bytes) { char* r = p; p += (bytes + 255) & ~(size_t)255; return r; };
    int* deg = (int*)alloc((size_t)N * 4);
    int* offs = (int*)alloc((size_t)(N + 1) * 4);
    int* cursor = (int*)alloc((size_t)N * 4);
    int* esrc = (int*)alloc((size_t)E * 4);
    unsigned short* Wc[3];
    for (int l = 0; l < 3; l++) Wc[l] = (unsigned short*)alloc(512 * 256 * 2);
    unsigned short* Wft = (unsigned short*)alloc(256 * 1024 * 2);
    unsigned short* Ucat = (unsigned short*)alloc((size_t)N * 1024 * 2);
    float* P = (float*)alloc((size_t)N * 256 * 4);
    unsigned short* Qb = (unsigned short*)alloc((size_t)N * 256 * 2);

    hipMemsetAsync(deg, 0, (size_t)N * 4, stream);
    int eb = (E + 255) / 256;
    count_kernel<<<eb, 256, 0, stream>>>(dst, E, deg);
    scan_kernel<<<1, 1024, 0, stream>>>(deg, offs, cursor, N);
    fill_kernel<<<eb, 256, 0, stream>>>(src, dst, E, cursor, esrc);

    int xblocks = (N * 256 + 2047) / 2048;
    prep_kernel<<<448 + xblocks, 256, 0, stream>>>(W[0], W[1], W[2], Wfp, x,
                                                   Wc[0], Wc[1], Wc[2], Wft, Ucat, N);

    int gm = (N + BM - 1) / BM;
    int ab = (N + 3) / 4;
    for (int l = 0; l < 3; l++) {
        gemm_kernel<0><<<dim3(gm, 4), 256, 0, stream>>>(Ucat + l * 256, Wc[l], nullptr,
                                                        P, Qb, nullptr, N, 256);
        agg_kernel<<<ab, 256, 0, stream>>>(P, Qb, b[l], offs, esrc, Ucat, (l + 1) * 256, N);
    }
    gemm_kernel<1><<<dim3(gm, 2), 256, 0, stream>>>(Ucat, Wft, bfp, nullptr, nullptr,
                                                    (float*)d_out, N, 1024);
}

// Round 3
// 318.893 us; speedup vs baseline: 1.1693x; 1.1693x over previous
//
#include <hip/hip_runtime.h>
#include <hip/hip_bf16.h>

// EdgeGNN: 3x EdgeConv(mean) + final linear.
// Algebra: out_i = relu( h_i @ (Wtop - Wbot) + mean_j(h_j @ Wbot) + b ), 0 if deg==0.
// => GEMM on dense H (P = H@(Wtop-Wbot), Q = H@Wbot), then gather-mean of Q.
// R3: 64x64 GEMM tiles (2504 blocks, ~8 blk/CU vs 2.4 before) + register prefetch pipeline.

typedef short short8 __attribute__((ext_vector_type(8)));
typedef float float4v __attribute__((ext_vector_type(4)));

static __device__ __forceinline__ float bf2f(unsigned short u) {
    union { unsigned int i; float f; } c; c.i = ((unsigned int)u) << 16; return c.f;
}
static __device__ __forceinline__ unsigned short f2bf(float f) {
    union { float f; unsigned int i; } c; c.f = f;
    unsigned int u = c.i;
    return (unsigned short)((u + 0x7FFFu + ((u >> 16) & 1u)) >> 16);  // RNE
}

// ---------------- CSR build ----------------
__global__ void count_kernel(const int* __restrict__ dst, int E, int* __restrict__ deg) {
    int idx = blockIdx.x * 256 + threadIdx.x;
    if (idx < E) atomicAdd(&deg[dst[idx]], 1);
}

__global__ __launch_bounds__(1024) void scan_kernel(const int* __restrict__ deg,
                                                    int* __restrict__ offs,
                                                    int* __restrict__ cursor, int N) {
    __shared__ int sh[1024];
    int t = threadIdx.x;
    int CH = (N + 1023) >> 10;
    int beg = t * CH, end = beg + CH; if (end > N) end = N; if (beg > N) beg = N;
    int s = 0;
    for (int i = beg; i < end; ++i) s += deg[i];
    sh[t] = s;
    __syncthreads();
    for (int off = 1; off < 1024; off <<= 1) {
        int v = 0;
        if (t >= off) v = sh[t - off];
        __syncthreads();
        if (t >= off) sh[t] += v;
        __syncthreads();
    }
    int run = (t > 0) ? sh[t - 1] : 0;
    for (int i = beg; i < end; ++i) {
        offs[i] = run; cursor[i] = run; run += deg[i];
    }
    if (t == 1023) offs[N] = sh[1023];
}

__global__ void fill_kernel(const int* __restrict__ src, const int* __restrict__ dst, int E,
                            int* __restrict__ cursor, int* __restrict__ esrc) {
    int idx = blockIdx.x * 256 + threadIdx.x;
    if (idx < E) {
        int p = atomicAdd(&cursor[dst[idx]], 1);
        esrc[p] = src[idx];
    }
}

// ---------------- fused prep: weight diff+transpose+bf16 (coalesced via LDS tiles) + x->bf16 ----
__global__ __launch_bounds__(256)
void prep_kernel(const float* __restrict__ W0, const float* __restrict__ W1,
                 const float* __restrict__ W2, const float* __restrict__ Wf,
                 const float* __restrict__ x,
                 unsigned short* __restrict__ Wc0, unsigned short* __restrict__ Wc1,
                 unsigned short* __restrict__ Wc2, unsigned short* __restrict__ Wft,
                 unsigned short* __restrict__ Ucat, int N) {
    __shared__ float ta[32][33];
    __shared__ float tb[32][33];
    int bb = blockIdx.x;
    int t = threadIdx.x;
    int r0 = t >> 5, c = t & 31;
    if (bb < 192) {
        const float* W = (bb < 64) ? W0 : (bb < 128) ? W1 : W2;
        unsigned short* Wc = (bb < 64) ? Wc0 : (bb < 128) ? Wc1 : Wc2;
        int t64 = bb & 63;
        int k0 = (t64 >> 3) * 32, n0 = (t64 & 7) * 32;
#pragma unroll
        for (int it = 0; it < 4; ++it) {
            int r = r0 + it * 8;
            float a = W[(k0 + r) * 256 + n0 + c];
            float bv = W[(k0 + r + 256) * 256 + n0 + c];
            ta[r][c] = a - bv;
            tb[r][c] = bv;
        }
        __syncthreads();
#pragma unroll
        for (int it = 0; it < 4; ++it) {
            int r = r0 + it * 8;  // row in n-space
            Wc[(n0 + r) * 256 + k0 + c] = f2bf(ta[c][r]);
            Wc[(256 + n0 + r) * 256 + k0 + c] = f2bf(tb[c][r]);
        }
    } else if (bb < 448) {
        int t256 = bb - 192;
        int k0 = (t256 >> 3) * 32, n0 = (t256 & 7) * 32;
#pragma unroll
        for (int it = 0; it < 4; ++it) {
            int r = r0 + it * 8;
            ta[r][c] = Wf[(k0 + r) * 256 + n0 + c];
        }
        __syncthreads();
#pragma unroll
        for (int it = 0; it < 4; ++it) {
            int r = r0 + it * 8;
            Wft[(n0 + r) * 1024 + k0 + c] = f2bf(ta[c][r]);
        }
    } else {
        long base = (long)(bb - 448) * 2048 + t * 8;
        if (base < (long)N * 256) {
            int i = (int)(base >> 8), cc = (int)(base & 255);
            const float4* xp = (const float4*)(x + base);
            float4 v0 = xp[0], v1 = xp[1];
            ushort4 w0, w1;
            w0.x = f2bf(v0.x); w0.y = f2bf(v0.y); w0.z = f2bf(v0.z); w0.w = f2bf(v0.w);
            w1.x = f2bf(v1.x); w1.y = f2bf(v1.y); w1.z = f2bf(v1.z); w1.w = f2bf(v1.w);
            unsigned short* up = Ucat + (long)i * 1024 + cc;
            *(ushort4*)up = w0;
            *(ushort4*)(up + 4) = w1;
        }
    }
}

// ---------------- bf16 MFMA GEMM, 64x64 tile, register-prefetch pipeline ----------------
// A: bf16, row stride 1024 (column window of Ucat). Bt: bf16 [outcols][K].
// MODE 0 (layer): grid.y=8; n<256 -> P fp32; n>=256 -> Qb bf16.
// MODE 1 (final): grid.y=4; out fp32 + bias.
#define LDK 72  // padded LDS row stride (elements): stride 36 dwords -> 2-way bank alias (free)

template <int MODE, int K>
__global__ __launch_bounds__(256)
void gemm_kernel(const unsigned short* __restrict__ A,
                 const unsigned short* __restrict__ Bt,
                 const float* __restrict__ bias,
                 float* __restrict__ P,
                 unsigned short* __restrict__ Qb,
                 float* __restrict__ outF,
                 int M) {
    __shared__ unsigned short ldsA[64 * LDK];
    __shared__ unsigned short ldsB[64 * LDK];
    int t = threadIdx.x;
    int bm = blockIdx.x, bn = blockIdx.y;
    int lane = t & 63, wave = t >> 6;
    int wm = wave >> 1, wn = wave & 1;
    int lr = lane & 15, q = lane >> 4;

    float4v acc[2][2];
#pragma unroll
    for (int i = 0; i < 2; i++)
#pragma unroll
        for (int j = 0; j < 2; j++) { float4v z = {0.f, 0.f, 0.f, 0.f}; acc[i][j] = z; }

    int r = t >> 2;        // staging row 0..63
    int quarter = t & 3;   // 16-element (32B) chunk within the 64-elem k-slice
    int rowA = bm * 64 + r;
    if (rowA >= M) rowA = M - 1;  // clamp: duplicate row, never stored
    const unsigned short* gA = A + (long)rowA * 1024 + quarter * 16;
    const unsigned short* gB = Bt + (long)(bn * 64 + r) * K + quarter * 16;
    unsigned short* sA = ldsA + r * LDK + quarter * 16;
    unsigned short* sB = ldsB + r * LDK + quarter * 16;

    // prologue: first tile into registers
    uint4 a0 = *(const uint4*)(gA);
    uint4 a1 = *(const uint4*)(gA + 8);
    uint4 b0 = *(const uint4*)(gB);
    uint4 b1 = *(const uint4*)(gB + 8);

#pragma unroll
    for (int k0 = 0; k0 < K; k0 += 64) {
        __syncthreads();  // previous iter's ds_reads done
        *(uint4*)sA = a0; *(uint4*)(sA + 8) = a1;
        *(uint4*)sB = b0; *(uint4*)(sB + 8) = b1;
        __syncthreads();
        if (k0 + 64 < K) {  // prefetch next tile; overlaps MFMA below
            a0 = *(const uint4*)(gA + k0 + 64);
            a1 = *(const uint4*)(gA + k0 + 72);
            b0 = *(const uint4*)(gB + k0 + 64);
            b1 = *(const uint4*)(gB + k0 + 72);
        }
#pragma unroll
        for (int ks = 0; ks < 2; ++ks) {
            short8 af[2], bfr[2];
#pragma unroll
            for (int mi = 0; mi < 2; ++mi)
                af[mi] = *(const short8*)(ldsA + (wm * 32 + mi * 16 + lr) * LDK + ks * 32 + q * 8);
#pragma unroll
            for (int ni = 0; ni < 2; ++ni)
                bfr[ni] = *(const short8*)(ldsB + (wn * 32 + ni * 16 + lr) * LDK + ks * 32 + q * 8);
#pragma unroll
            for (int mi = 0; mi < 2; ++mi)
#pragma unroll
                for (int ni = 0; ni < 2; ++ni)
                    acc[mi][ni] = __builtin_amdgcn_mfma_f32_16x16x32_bf16(af[mi], bfr[ni], acc[mi][ni], 0, 0, 0);
        }
    }

    int nBase = bn * 64 + wn * 32;
    int rowBase = bm * 64 + wm * 32;
#pragma unroll
    for (int mi = 0; mi < 2; ++mi) {
#pragma unroll
        for (int ni = 0; ni < 2; ++ni) {
            int n = nBase + ni * 16 + lr;
            int row0 = rowBase + mi * 16 + q * 4;
#pragma unroll
            for (int rr4 = 0; rr4 < 4; ++rr4) {
                int rr = row0 + rr4;
                if (rr < M) {
                    float v = acc[mi][ni][rr4];
                    if (MODE == 0) {
                        if (n < 256) P[(long)rr * 256 + n] = v;
                        else Qb[(long)rr * 256 + (n - 256)] = f2bf(v);
                    } else {
                        outF[(long)rr * 256 + n] = v + bias[n];
                    }
                }
            }
        }
    }
}

// ---------------- gather-mean + epilogue: one wave per node ----------------
__global__ __launch_bounds__(256)
void agg_kernel(const float* __restrict__ P, const unsigned short* __restrict__ Qb,
                const float* __restrict__ bias,
                const int* __restrict__ offs, const int* __restrict__ esrc,
                unsigned short* __restrict__ Ucat, int colOff, int N) {
    int wave = threadIdx.x >> 6, lane = threadIdx.x & 63;
    int i = blockIdx.x * 4 + wave;
    if (i >= N) return;
    int c = lane * 4;
    float4 pv = *(const float4*)(P + (long)i * 256 + c);
    float4 bv = *(const float4*)(bias + c);
    float a0 = 0.f, a1 = 0.f, a2 = 0.f, a3 = 0.f;
    int e0 = offs[i], e1 = offs[i + 1];
    int e = e0;
    for (; e + 4 <= e1; e += 4) {  // 4 outstanding gathers for MLP
        int s0 = esrc[e], s1 = esrc[e + 1], s2 = esrc[e + 2], s3 = esrc[e + 3];
        ushort4 r0 = *(const ushort4*)(Qb + (long)s0 * 256 + c);
        ushort4 r1 = *(const ushort4*)(Qb + (long)s1 * 256 + c);
        ushort4 r2 = *(const ushort4*)(Qb + (long)s2 * 256 + c);
        ushort4 r3 = *(const ushort4*)(Qb + (long)s3 * 256 + c);
        a0 += (bf2f(r0.x) + bf2f(r1.x)) + (bf2f(r2.x) + bf2f(r3.x));
        a1 += (bf2f(r0.y) + bf2f(r1.y)) + (bf2f(r2.y) + bf2f(r3.y));
        a2 += (bf2f(r0.z) + bf2f(r1.z)) + (bf2f(r2.z) + bf2f(r3.z));
        a3 += (bf2f(r0.w) + bf2f(r1.w)) + (bf2f(r2.w) + bf2f(r3.w));
    }
    for (; e < e1; ++e) {
        int s0 = esrc[e];
        ushort4 r0 = *(const ushort4*)(Qb + (long)s0 * 256 + c);
        a0 += bf2f(r0.x); a1 += bf2f(r0.y); a2 += bf2f(r0.z); a3 += bf2f(r0.w);
    }
    int d = e1 - e0;
    float inv = (d > 0) ? 1.0f / (float)d : 0.0f;
    ushort4 w;
    float v0 = (d > 0) ? fmaxf(pv.x + a0 * inv + bv.x, 0.f) : 0.f;
    float v1 = (d > 0) ? fmaxf(pv.y + a1 * inv + bv.y, 0.f) : 0.f;
    float v2 = (d > 0) ? fmaxf(pv.z + a2 * inv + bv.z, 0.f) : 0.f;
    float v3 = (d > 0) ? fmaxf(pv.w + a3 * inv + bv.w, 0.f) : 0.f;
    w.x = f2bf(v0); w.y = f2bf(v1); w.z = f2bf(v2); w.w = f2bf(v3);
    *(ushort4*)(Ucat + (long)i * 1024 + colOff + c) = w;
}

extern "C" void kernel_launch(void* const* d_in, const int* in_sizes, int n_in,
                              void* d_out, int out_size, void* d_ws, size_t ws_size,
                              hipStream_t stream) {
    const float* x = (const float*)d_in[0];
    const int* ei = (const int*)d_in[1];
    const float* W[3] = {(const float*)d_in[2], (const float*)d_in[4], (const float*)d_in[6]};
    const float* b[3] = {(const float*)d_in[3], (const float*)d_in[5], (const float*)d_in[7]};
    const float* Wfp = (const float*)d_in[8];
    const float* bfp = (const float*)d_in[9];

    int N = in_sizes[0] / 256;
    int E = in_sizes[1] / 2;
    const int* src = ei;
    const int* dst = ei + E;

    char* p = (char*)d_ws;
    auto alloc = [&](size_t bytes) { char* r = p; p += (bytes + 255) & ~(size_t)255; return r; };
    int* deg = (int*)alloc((size_t)N * 4);
    int* offs = (int*)alloc((size_t)(N + 1) * 4);
    int* cursor = (int*)alloc((size_t)N * 4);
    int* esrc = (int*)alloc((size_t)E * 4);
    unsigned short* Wc[3];
    for (int l = 0; l < 3; l++) Wc[l] = (unsigned short*)alloc(512 * 256 * 2);
    unsigned short* Wft = (unsigned short*)alloc(256 * 1024 * 2);
    unsigned short* Ucat = (unsigned short*)alloc((size_t)N * 1024 * 2);
    float* P = (float*)alloc((size_t)N * 256 * 4);
    unsigned short* Qb = (unsigned short*)alloc((size_t)N * 256 * 2);

    hipMemsetAsync(deg, 0, (size_t)N * 4, stream);
    int eb = (E + 255) / 256;
    count_kernel<<<eb, 256, 0, stream>>>(dst, E, deg);
    scan_kernel<<<1, 1024, 0, stream>>>(deg, offs, cursor, N);
    fill_kernel<<<eb, 256, 0, stream>>>(src, dst, E, cursor, esrc);

    int xblocks = (N * 256 + 2047) / 2048;
    prep_kernel<<<448 + xblocks, 256, 0, stream>>>(W[0], W[1], W[2], Wfp, x,
                                                   Wc[0], Wc[1], Wc[2], Wft, Ucat, N);

    int gm = (N + 63) / 64;  // 313
    int ab = (N + 3) / 4;
    for (int l = 0; l < 3; l++) {
        gemm_kernel<0, 256><<<dim3(gm, 8), 256, 0, stream>>>(Ucat + l * 256, Wc[l], nullptr,
                                                             P, Qb, nullptr, N);
        agg_kernel<<<ab, 256, 0, stream>>>(P, Qb, b[l], offs, esrc, Ucat, (l + 1) * 256, N);
    }
    gemm_kernel<1, 1024><<<dim3(gm, 4), 256, 0, stream>>>(Ucat, Wft, bfp, nullptr, nullptr,
                                                          (float*)d_out, N);
}